// Round 5
// baseline (232.972 us; speedup 1.0000x reference)
//
#include <hip/hip_runtime.h>
#include <stdint.h>

// u   = 0.01 * (x @ x2h)   [B=524288, K=32, N=256]
// spk = zeros              [B, 256]
// h2h is dead (recurrent state is zero for the single time step).
//
// Single dispatch, role-split blocks (blockIdx%16): 9/16 compute u via the
// proven wave-private staged GEMV (global_load_lds width=16, double-buffered,
// counted vmcnt, no barriers, weights in VGPRs); 7/16 do a grid-stride
// nontemporal float4 fill of spk. Fill waves keep HBM write queues full while
// compute waves sit in load-wait/VALU phases.

#define NHID 256
#define NINP 32
#define RPC  8          // rows per chunk: 8*128B = 1 KB = one global_load_lds_dwordx4/wave

#define BLOCKS_TOTAL 4096
#define COMP_PER16   9                       // compute blocks per 16
#define FILL_PER16   (16 - COMP_PER16)
#define NCOMP_BLOCKS (BLOCKS_TOTAL / 16 * COMP_PER16)   // 2304
#define NFILL_BLOCKS (BLOCKS_TOTAL / 16 * FILL_PER16)   // 1792

typedef float __attribute__((ext_vector_type(4))) f32x4;
typedef float __attribute__((ext_vector_type(2))) f32x2;

__device__ __forceinline__ void stage_chunk(const float* src_lane, void* lds_wave_base) {
    // global src is per-lane; LDS dst is wave-uniform base + lane*16 (HW rule).
    __builtin_amdgcn_global_load_lds(
        (const __attribute__((address_space(1))) uint32_t*)src_lane,
        (__attribute__((address_space(3))) uint32_t*)lds_wave_base,
        16, 0, 0);
}

__global__ __launch_bounds__(256, 4) void lsm_kernel(
    const float* __restrict__ x, const float* __restrict__ x2h,
    float* __restrict__ u, float* __restrict__ spk, int B)
{
    __shared__ float xbuf[4][2][RPC * NINP];   // 4 waves x double-buffer x 1 KB = 8 KB

    const int b16 = blockIdx.x & 15;

    if (b16 >= COMP_PER16) {
        // ---------------- fill role: spk = 0, linear nontemporal float4 ----------------
        const int fb = (blockIdx.x >> 4) * FILL_PER16 + (b16 - COMP_PER16);
        const size_t nf4 = (size_t)B * NHID / 4;                 // 33,554,432 float4
        const size_t stride = (size_t)NFILL_BLOCKS * 256;
        f32x4* spk4 = (f32x4*)spk;
        f32x4 z = {0.f, 0.f, 0.f, 0.f};
        for (size_t j = (size_t)fb * 256 + threadIdx.x; j < nf4; j += stride)
            __builtin_nontemporal_store(z, spk4 + j);
        return;
    }

    // ---------------- compute role: u = 0.01 * x @ x2h ----------------
    const int cb   = (blockIdx.x >> 4) * COMP_PER16 + b16;
    const int lane = threadIdx.x & 63;
    const int wv   = threadIdx.x >> 6;
    const int wid  = __builtin_amdgcn_readfirstlane(cb * 4 + wv);

    // Wave pair: even wave = cols [0,128), odd wave = cols [128,256).
    const int c = (wid & 1) * 128 + lane * 2;

    // Lane owns 2 columns; weights pre-scaled by RC*DT = 0.01. 64 VGPRs.
    f32x2 w[NINP];
#pragma unroll
    for (int k = 0; k < NINP; ++k) {
        f32x2 t = *reinterpret_cast<const f32x2*>(x2h + k * NHID + c);
        w[k] = t * 0.01f;
    }

    const int cw  = wid >> 1;                  // pair id
    const int ncw = NCOMP_BLOCKS * 4 / 2;      // 4608 pairs
    const int total_chunks = B / RPC;          // 65536
    const int nch = (total_chunks - cw + ncw - 1) / ncw;   // 14 or 15
    if (nch <= 0) return;

    const float* src0 = x + (size_t)cw * (RPC * NINP) + lane * 4;
    const size_t src_stride = (size_t)ncw * (RPC * NINP);  // floats per chunk step

    stage_chunk(src0, &xbuf[wv][0][0]);
    if (nch > 1) stage_chunk(src0 + src_stride, &xbuf[wv][1][0]);

    for (int i = 0; i < nch; ++i) {
        // Counted waits (L=stage load, S=u store). Iter body: [wait][8xS][L(i+2)].
        //   i==0: ops newer than L0 = {L1}                  -> vmcnt(1)
        //   mid:  ops newer than Li = {S(i-1) x8, L(i+1)}   -> vmcnt(9)
        //   last: ops newer than Ln = {S(n-1) x8}           -> vmcnt(8)
        if (i == 0) {
            if (nch > 1) asm volatile("s_waitcnt vmcnt(1)" ::: "memory");
            else         asm volatile("s_waitcnt vmcnt(0)" ::: "memory");
        } else if (i == nch - 1) {
            asm volatile("s_waitcnt vmcnt(8)" ::: "memory");
        } else {
            asm volatile("s_waitcnt vmcnt(9)" ::: "memory");
        }

        const float* xb = &xbuf[wv][i & 1][0];
        const size_t row0 = ((size_t)cw + (size_t)i * ncw) * RPC;

#pragma unroll 2
        for (int r = 0; r < RPC; ++r) {
            // uniform-address LDS reads -> free 16B broadcast to all lanes
            const f32x4* xr = (const f32x4*)(xb + r * NINP);
            f32x2 acc = {0.f, 0.f};
#pragma unroll
            for (int g = 0; g < 8; ++g) {
                f32x4 xq = xr[g];
                acc += w[4 * g + 0] * xq.x;
                acc += w[4 * g + 1] * xq.y;
                acc += w[4 * g + 2] * xq.z;
                acc += w[4 * g + 3] * xq.w;
            }
            __builtin_nontemporal_store(acc, (f32x2*)(u + (row0 + r) * NHID + c));
        }

        if (i + 2 < nch) stage_chunk(src0 + (size_t)(i + 2) * src_stride, &xbuf[wv][i & 1][0]);
    }
}

extern "C" void kernel_launch(void* const* d_in, const int* in_sizes, int n_in,
                              void* d_out, int out_size, void* d_ws, size_t ws_size,
                              hipStream_t stream) {
    const float* x   = (const float*)d_in[0];
    const float* x2h = (const float*)d_in[1];
    // d_in[2] (h2h) is dead: recurrent input state is zero.

    const int B = in_sizes[0] / NINP;            // 524288
    float* u   = (float*)d_out;
    float* spk = u + (size_t)B * NHID;

    lsm_kernel<<<BLOCKS_TOTAL, 256, 0, stream>>>(x, x2h, u, spk, B);
}

// Round 6
// 226.617 us; speedup vs baseline: 1.0280x; 1.0280x over previous
//
#include <hip/hip_runtime.h>
#include <stdint.h>

// u   = 0.01 * (x @ x2h)   [B=524288, K=32, N=256]
// spk = zeros              [B, 256]
// h2h is dead (recurrent state is zero for the single time step).
//
// Producer/consumer wave split (vmcnt store-drain decoupling):
//   vmcnt retires IN ISSUE ORDER, so a wave that issues stores then waits on a
//   later load transitively drains ALL its older stores to HBM -> serializes.
//   Here wave 4 of each block only LOADS (global_load_lds, quad-buffer,
//   counted vmcnt(2)); waves 0-3 only COMPUTE+STORE and never execute a
//   vmcnt wait, so their nontemporal stores flow like the 6.6 TB/s fill
//   kernel. Sync = raw s_barrier (no implicit waitcnt drain).

#define NHID 256
#define NINP 32
#define RPC  8            // rows per chunk: 8*128B = 1 KB = one global_load_lds_dwordx4
#define NBUF 4            // quad buffer -> stage depth 2 with overwrite safety
#define BLOCKS 2048       // 65536 chunks / 2048 = 32 chunks per block exactly

typedef float __attribute__((ext_vector_type(4))) f32x4;

__device__ __forceinline__ void stage_chunk(const float* src_lane, void* lds_base) {
    // global src is per-lane (lane*16B); LDS dst is wave-uniform base (HW rule).
    __builtin_amdgcn_global_load_lds(
        (const __attribute__((address_space(1))) uint32_t*)src_lane,
        (__attribute__((address_space(3))) uint32_t*)lds_base,
        16, 0, 0);
}

__global__ __launch_bounds__(320) void lsm_kernel(
    const float* __restrict__ x, const float* __restrict__ x2h,
    float* __restrict__ u, float* __restrict__ spk, int B)
{
    __shared__ float xbuf[NBUF][RPC * NINP];    // 4 x 1 KB

    const int lane = threadIdx.x & 63;
    const int wv   = threadIdx.x >> 6;          // 0..3 consumers, 4 producer
    const int nch  = (B / RPC) / BLOCKS;        // 32
    const size_t chunk0 = (size_t)blockIdx.x * nch;

    if (wv == 4) {
        // -------- producer: pure loads, counted vmcnt, never any store --------
        const float* src = x + chunk0 * (RPC * NINP) + lane * 4;
        const size_t stride = RPC * NINP;       // floats per chunk
        stage_chunk(src, &xbuf[0][0]);
        if (nch > 1) stage_chunk(src + stride, &xbuf[1][0]);
        for (int k = 0; k < nch; ++k) {
            // stage c(k+2) into buf[(k+2)&3]: consumers finished that buffer
            // (chunk k-2) before they arrived at barrier k-1 -> safe now.
            if (k + 2 < nch) stage_chunk(src + (size_t)(k + 2) * stride, &xbuf[(k + 2) & 3][0]);
            // Need L(k) complete; outstanding newer loads: L(k+1), L(k+2).
            if (k + 2 < nch)      asm volatile("s_waitcnt vmcnt(2)" ::: "memory");
            else if (k + 1 < nch) asm volatile("s_waitcnt vmcnt(1)" ::: "memory");
            else                  asm volatile("s_waitcnt vmcnt(0)" ::: "memory");
            asm volatile("s_barrier" ::: "memory");   // barrier k: buf[k&3] ready
        }
        return;
    }

    // -------- consumers: ds_read broadcast + FMA + stores, NO vmcnt waits --------
    const int c = wv * 64 + lane;               // each wave owns 64 consecutive cols
    float w[NINP];                               // weights pre-scaled by RC*DT = 0.01
#pragma unroll
    for (int k = 0; k < NINP; ++k) w[k] = x2h[k * NHID + c] * 0.01f;

    for (int k = 0; k < nch; ++k) {
        asm volatile("s_barrier" ::: "memory");  // barrier k: producer filled buf[k&3]
        const float* xb = &xbuf[k & 3][0];
        const size_t row0 = (chunk0 + k) * RPC;
#pragma unroll
        for (int r = 0; r < RPC; ++r) {
            const f32x4* xr = (const f32x4*)(xb + r * NINP);   // uniform addr -> broadcast
            float acc = 0.f;
#pragma unroll
            for (int g = 0; g < 8; ++g) {
                f32x4 xq = xr[g];
                acc += w[4 * g + 0] * xq.x;
                acc += w[4 * g + 1] * xq.y;
                acc += w[4 * g + 2] * xq.z;
                acc += w[4 * g + 3] * xq.w;
            }
            const size_t base = (row0 + r) * NHID + c;
            __builtin_nontemporal_store(acc, u + base);        // 256B/wave-instr
            __builtin_nontemporal_store(0.f, spk + base);
        }
        // all ds_reads of this chunk already lgkmcnt-waited (FMA deps) before
        // we arrive at the next barrier -> producer may overwrite after it.
    }
}

extern "C" void kernel_launch(void* const* d_in, const int* in_sizes, int n_in,
                              void* d_out, int out_size, void* d_ws, size_t ws_size,
                              hipStream_t stream) {
    const float* x   = (const float*)d_in[0];
    const float* x2h = (const float*)d_in[1];
    // d_in[2] (h2h) is dead: recurrent input state is zero.

    const int B = in_sizes[0] / NINP;            // 524288
    float* u   = (float*)d_out;
    float* spk = u + (size_t)B * NHID;

    lsm_kernel<<<BLOCKS, 320, 0, stream>>>(x, x2h, u, spk, B);
}